// Round 7
// baseline (252.378 us; speedup 1.0000x reference)
//
#include <hip/hip_runtime.h>

// TeacherEmbeddingTransform: block-diagonal GEMM, fp32.
//   x: (16384, 2304), weight: (25600,1) flat, bias: (576,), out: (16384, 576)
//   Blocks: 16x [16->4], 32x [32->8], 16x [64->16]
// Memory-bound: 151 MB read + 38 MB write => ~30 us floor at 6.3 TB/s.
//
// v6 = v5 + non-temporal hints ONLY.
//   v5 (XCD write-pairing swizzle) was a real ~7 us kernel win (residual
//   52 -> 45 us vs in-window fills), confirming the write/L2-locality axis.
//   Remaining gap to the ~30 us floor: suspected L2 write-allocate RMW on
//   `out` (write-once data: every 128 B line fetched from HBM before being
//   dirtied = +38 MB hidden FETCH ~ +6 us) plus x polluting L2 (x bytes are
//   read exactly once across the grid -> caching them is pure victim
//   traffic against the write path).
//   - out store: __builtin_nontemporal_store (no allocate/RMW)
//   - x staging: __builtin_nontemporal_load (don't pollute L2)
//   - weights/bias: normal cached loads (reused by all 256 row-tiles)
//   Everything else byte-identical to v5 (proven): XCD-pairing remap so the
//   two wgs writing the two 64 B halves of each 128 B out-line share an XCD
//   and are dispatched 8 apart; scalar-path weights; sparsity k-loops;
//   17.4 KB LDS -> 32 waves/CU.
// If this nulls: ledger complete (LDS 4x, VALU 1.44x, occupancy 4x, weight
// path, write locality, cache hints) -> kernel is DRAM-pattern-bound at its
// measurable floor -> declare roofline.

#define BATCH   16384
#define IN_DIM  2304
#define OUT_DIM 576
#define CHUNKS  36
#define XS_LDW  68   // 64 + 4 pad; b128 rows hit the 8-cyc floor, conflict-free
#define ROWS_WG 64

typedef float f4 __attribute__((ext_vector_type(4)));

// NK = k-quads in this block, CH = block's output width (w row stride).
template<int NK, int CH>
__device__ __forceinline__ void col_fma(const float* __restrict__ xrow,
                                        const float* __restrict__ wp,
                                        float4& acc)
{
    #pragma unroll
    for (int t = 0; t < NK; ++t) {
        const int k = t << 2;
        const float4 xv = *reinterpret_cast<const float4*>(xrow + k);
        const float4 w0 = *reinterpret_cast<const float4*>(wp + (k + 0) * CH);
        const float4 w1 = *reinterpret_cast<const float4*>(wp + (k + 1) * CH);
        const float4 w2 = *reinterpret_cast<const float4*>(wp + (k + 2) * CH);
        const float4 w3 = *reinterpret_cast<const float4*>(wp + (k + 3) * CH);
        acc.x += xv.x*w0.x + xv.y*w1.x + xv.z*w2.x + xv.w*w3.x;
        acc.y += xv.x*w0.y + xv.y*w1.y + xv.z*w2.y + xv.w*w3.y;
        acc.z += xv.x*w0.z + xv.y*w1.z + xv.z*w2.z + xv.w*w3.z;
        acc.w += xv.x*w0.w + xv.y*w1.w + xv.z*w2.w + xv.w*w3.w;
    }
}

__global__ __launch_bounds__(256) void fused_block_mm(
    const float* __restrict__ x, const float* __restrict__ w,
    const float* __restrict__ bias, float* __restrict__ out)
{
    __shared__ float xs[ROWS_WG * XS_LDW];   // 17,408 B

    const int tid = threadIdx.x;
    const int bx  = blockIdx.x;

    // ---- XCD-pairing remap: line-sharing wg pairs land on one XCD ----
    const int xcd = bx & 7;
    const int g   = bx >> 3;
    const int m   = g & 1;                   // pair member (cj parity)
    const int p   = ((g >> 1) << 3) + xcd;   // pair id 0..4607
    const int rt  = p / 18;                  // row tile 0..255
    const int cj  = ((p % 18) << 1) + m;     // chunk id 0..35 (wg-uniform)
    const int row_base = rt * ROWS_WG;

    // ---- stage x tile: 64 rows x 64 cols, nt float4 (x is read-once) ----
    const float* __restrict__ xsrc = x + (size_t)row_base * IN_DIM + cj * 64;
    #pragma unroll
    for (int i = 0; i < 4; ++i) {
        const int f = tid + (i << 8), r = f >> 4, c = (f & 15) << 2;
        const f4 v = __builtin_nontemporal_load(
            reinterpret_cast<const f4*>(xsrc + (size_t)r * IN_DIM + c));
        *reinterpret_cast<f4*>(&xs[r * XS_LDW + c]) = v;
    }
    __syncthreads();

    // ---- compute: wave wv -> out cols cj*16+4wv..+3, lane = row ----
    const int wv   = tid >> 6;
    const int lane = tid & 63;
    const int ocol = cj * 16 + (wv << 2);

    float4 acc = *reinterpret_cast<const float4*>(bias + ocol);
    const float* xrow = &xs[lane * XS_LDW];

    if (cj < 4) {
        // group 1: 4 blocks of 16->4; wave's block = wv, k in [16wv, 16wv+16)
        const int woff = __builtin_amdgcn_readfirstlane(cj * 256 + wv * 64);
        col_fma<4, 4>(xrow + (wv << 4), w + woff, acc);
    } else if (cj < 20) {
        // group 2: 2 blocks of 32->8; block = wv>>1, c0 = (wv&1)*4
        const int woff = __builtin_amdgcn_readfirstlane(
            1024 + (cj - 4) * 512 + ((wv >> 1) << 8) + ((wv & 1) << 2));
        col_fma<8, 8>(xrow + ((wv >> 1) << 5), w + woff, acc);
    } else {
        // group 3: 1 dense 64->16 block; c0 = 4wv
        const int woff = __builtin_amdgcn_readfirstlane(
            9216 + (cj - 20) * 1024 + (wv << 2));
        col_fma<16, 16>(xrow, w + woff, acc);
    }

    // ---- store: nt float4 per lane (write-once data, skip L2 allocate) ----
    float* __restrict__ op =
        out + (size_t)(row_base + lane) * OUT_DIM + ocol;
    const f4 av = { acc.x, acc.y, acc.z, acc.w };
    __builtin_nontemporal_store(av, reinterpret_cast<f4*>(op));
}

extern "C" void kernel_launch(void* const* d_in, const int* in_sizes, int n_in,
                              void* d_out, int out_size, void* d_ws, size_t ws_size,
                              hipStream_t stream) {
    const float* x    = (const float*)d_in[0];
    const float* w    = (const float*)d_in[1];
    const float* bias = (const float*)d_in[2];
    float* out        = (float*)d_out;

    const int row_tiles = BATCH / ROWS_WG;           // 256
    fused_block_mm<<<dim3(CHUNKS * row_tiles), 256, 0, stream>>>(
        x, w, bias, out);
}

// Round 8
// 229.004 us; speedup vs baseline: 1.1021x; 1.1021x over previous
//
#include <hip/hip_runtime.h>

// TeacherEmbeddingTransform: block-diagonal GEMM, fp32.
//   x: (16384, 2304), weight: (25600,1) flat, bias: (576,), out: (16384, 576)
//   Blocks: 16x [16->4], 32x [32->8], 16x [64->16]
// Memory-bound: 151 MB read + 38 MB write => ~30 us floor at 6.3 TB/s.
//
// v7: intra-wg full-line writes (256 thr). Ledger so far:
//   LDS traffic 4x: null. VALU 1.44x: null. Occupancy 4x: null. Scalar vs
//   LDS weights: null. v5 XCD write-pairing: +7 us (kernel ~52->~45).
//   v6 nt hints: -30 us REGRESSION -> L2 write-combining of the two 64 B
//   line-halves is real and valuable; bypassing it is disastrous.
//   => push the only productive axis to its endpoint: ONE wg owns each
//   128 B out-line (no cross-wg dispatch-skew, no XCD-mapping assumption).
//   - wg = 256 thr (4 waves), 64 rows, chunk PAIR cp -> out cols
//     32cp..32cp+31 = exactly one 128 B line per row. Pairs never straddle
//     groups (boundaries 4, 20 even).
//   - lane = row; wave wv computes quad wv of BOTH chunks (two float4 accs,
//     two wave-uniform scalar weight bases -> proven s_load path x2).
//   - reads: 512 B contiguous per row per wg (vs v5's 256 B).
//   - stores: cached float4 x2 per lane (v6 proved nt bypass hurts).
//   - LDS 33.8 KB (XS_LDW=132, 132%32=4 -> same free 2-way bank step),
//     4 wg/CU = 16 waves/CU (occupancy axis falsified down to 8).
// If this nulls at ~226: write axis exhausted -> roofline, revert to best.

#define BATCH   16384
#define IN_DIM  2304
#define OUT_DIM 576
#define CPAIRS  18
#define XS_LDW  132  // 128 + 4 pad; row step = 4 banks -> b128 2-way (free)
#define ROWS_WG 64

// NK = k-quads in this block, CH = block's output width (w row stride).
template<int NK, int CH>
__device__ __forceinline__ void col_fma(const float* __restrict__ xrow,
                                        const float* __restrict__ wp,
                                        float4& acc)
{
    #pragma unroll
    for (int t = 0; t < NK; ++t) {
        const int k = t << 2;
        const float4 xv = *reinterpret_cast<const float4*>(xrow + k);
        const float4 w0 = *reinterpret_cast<const float4*>(wp + (k + 0) * CH);
        const float4 w1 = *reinterpret_cast<const float4*>(wp + (k + 1) * CH);
        const float4 w2 = *reinterpret_cast<const float4*>(wp + (k + 2) * CH);
        const float4 w3 = *reinterpret_cast<const float4*>(wp + (k + 3) * CH);
        acc.x += xv.x*w0.x + xv.y*w1.x + xv.z*w2.x + xv.w*w3.x;
        acc.y += xv.x*w0.y + xv.y*w1.y + xv.z*w2.y + xv.w*w3.y;
        acc.z += xv.x*w0.z + xv.y*w1.z + xv.z*w2.z + xv.w*w3.z;
        acc.w += xv.x*w0.w + xv.y*w1.w + xv.z*w2.w + xv.w*w3.w;
    }
}

__global__ __launch_bounds__(256) void fused_block_mm(
    const float* __restrict__ x, const float* __restrict__ w,
    const float* __restrict__ bias, float* __restrict__ out)
{
    __shared__ float xs[ROWS_WG * XS_LDW];   // 33,792 B

    const int tid = threadIdx.x;
    const int bx  = blockIdx.x;
    const int cp  = bx % CPAIRS;             // chunk pair 0..17 (wg-uniform)
    const int rt  = bx / CPAIRS;             // row tile 0..255
    const int row_base = rt * ROWS_WG;
    const int cjA = cp << 1;                 // first chunk of the pair
    const int cjB = cjA + 1;

    // ---- stage x tile: 64 rows x 128 cols, 512 B contiguous per row ----
    const float* __restrict__ xsrc = x + (size_t)row_base * IN_DIM + cjA * 64;
    #pragma unroll
    for (int i = 0; i < 8; ++i) {
        const int f = tid + (i << 8), r = f >> 5, c = (f & 31) << 2;
        *reinterpret_cast<float4*>(&xs[r * XS_LDW + c]) =
            *reinterpret_cast<const float4*>(xsrc + (size_t)r * IN_DIM + c);
    }
    __syncthreads();

    // ---- compute: wave wv -> quad wv of BOTH chunks; lane = row ----
    const int wv   = tid >> 6;               // 0..3
    const int lane = tid & 63;
    const int ocolA = cjA * 16 + (wv << 2);  // chunk B cols = +16

    float4 accA = *reinterpret_cast<const float4*>(bias + ocolA);
    float4 accB = *reinterpret_cast<const float4*>(bias + ocolA + 16);
    const float* xrowA = &xs[lane * XS_LDW];       // chunk A k-cols 0..63
    const float* xrowB = xrowA + 64;               // chunk B k-cols 64..127

    if (cjA < 4) {
        // group 1: 4 blocks of 16->4; wave's block = wv, k in [16wv, 16wv+16)
        const int woffA = __builtin_amdgcn_readfirstlane(cjA * 256 + wv * 64);
        const int woffB = __builtin_amdgcn_readfirstlane(cjB * 256 + wv * 64);
        col_fma<4, 4>(xrowA + (wv << 4), w + woffA, accA);
        col_fma<4, 4>(xrowB + (wv << 4), w + woffB, accB);
    } else if (cjA < 20) {
        // group 2: 2 blocks of 32->8; block = wv>>1, c0 = (wv&1)*4
        const int woffA = __builtin_amdgcn_readfirstlane(
            1024 + (cjA - 4) * 512 + ((wv >> 1) << 8) + ((wv & 1) << 2));
        const int woffB = __builtin_amdgcn_readfirstlane(
            1024 + (cjB - 4) * 512 + ((wv >> 1) << 8) + ((wv & 1) << 2));
        col_fma<8, 8>(xrowA + ((wv >> 1) << 5), w + woffA, accA);
        col_fma<8, 8>(xrowB + ((wv >> 1) << 5), w + woffB, accB);
    } else {
        // group 3: 1 dense 64->16 block; c0 = 4wv
        const int woffA = __builtin_amdgcn_readfirstlane(
            9216 + (cjA - 20) * 1024 + (wv << 2));
        const int woffB = __builtin_amdgcn_readfirstlane(
            9216 + (cjB - 20) * 1024 + (wv << 2));
        col_fma<16, 16>(xrowA, w + woffA, accA);
        col_fma<16, 16>(xrowB, w + woffB, accB);
    }

    // ---- store: 2x float4 per lane; 4 waves x 2 = full 128 B line/row ----
    float* __restrict__ op =
        out + (size_t)(row_base + lane) * OUT_DIM + ocolA;
    *reinterpret_cast<float4*>(op)      = accA;
    *reinterpret_cast<float4*>(op + 16) = accB;
}

extern "C" void kernel_launch(void* const* d_in, const int* in_sizes, int n_in,
                              void* d_out, int out_size, void* d_ws, size_t ws_size,
                              hipStream_t stream) {
    const float* x    = (const float*)d_in[0];
    const float* w    = (const float*)d_in[1];
    const float* bias = (const float*)d_in[2];
    float* out        = (float*)d_out;

    const int row_tiles = BATCH / ROWS_WG;           // 256
    fused_block_mm<<<dim3(CPAIRS * row_tiles), 256, 0, stream>>>(
        x, w, bias, out);
}

// Round 9
// 224.663 us; speedup vs baseline: 1.1234x; 1.0193x over previous
//
#include <hip/hip_runtime.h>

// TeacherEmbeddingTransform: block-diagonal GEMM, fp32.
//   x: (16384, 2304), weight: (25600,1) flat, bias: (576,), out: (16384, 576)
//   Blocks: 16x [16->4], 32x [32->8], 16x [64->16]
// Memory-bound: 151 MB read + 38 MB write => ~30 us floor at 6.3 TB/s.
//
// v8 = v3 body (proven) + row-tile-per-XCD remap (full stream density).
//   Ledger: LDS 4x null; VALU 1.44x null; occupancy 4x null; weight path
//   null; v5 pair-per-XCD swizzle +7 us; v6 nt bypass -30 us (L2 write
//   combining is real); v7 intra-wg full lines WITHOUT the swizzle: gave
//   v5's win back -> the winning mechanism is per-XCD STREAM DENSITY, not
//   line ownership per se.
//   Endpoint of that axis: all 36 chunks of one row-tile on ONE XCD,
//   dispatched consecutively. Under round-robin XCD = bx%8 (the assumption
//   v5's win validated):
//     x8 = bx&7; q = bx>>3; cj = q%36; g = q/36; rt = 8g + x8   (bijective)
//   -> each XCD serially walks cj=0..35 of its row-tile: reads arrive as
//   dense 590 KB contiguous windows (64 full x rows), writes as dense
//   147 KB windows with every 128 B out-line assembled inside one L2
//   (subsumes v7's goal). Concurrent footprint/XCD ~ 256 wg x 16 KB ~ 4 MB
//   ~ one L2.
//   Kernel body byte-identical to v3: 256 thr, lane=row, scalar-path
//   weights (readfirstlane -> s_load), sparsity k-loops NK=4/8/16,
//   XS_LDW=68, 17.4 KB LDS -> 32 waves/CU.
// If null at ~226-229: stream-density axis exhausted -> roofline, revert
// to best measured (v5).

#define BATCH   16384
#define IN_DIM  2304
#define OUT_DIM 576
#define CHUNKS  36
#define XS_LDW  68   // 64 + 4 pad; b128 rows hit the 8-cyc floor, conflict-free
#define ROWS_WG 64

// NK = k-quads in this block, CH = block's output width (w row stride).
template<int NK, int CH>
__device__ __forceinline__ void col_fma(const float* __restrict__ xrow,
                                        const float* __restrict__ wp,
                                        float4& acc)
{
    #pragma unroll
    for (int t = 0; t < NK; ++t) {
        const int k = t << 2;
        const float4 xv = *reinterpret_cast<const float4*>(xrow + k);
        const float4 w0 = *reinterpret_cast<const float4*>(wp + (k + 0) * CH);
        const float4 w1 = *reinterpret_cast<const float4*>(wp + (k + 1) * CH);
        const float4 w2 = *reinterpret_cast<const float4*>(wp + (k + 2) * CH);
        const float4 w3 = *reinterpret_cast<const float4*>(wp + (k + 3) * CH);
        acc.x += xv.x*w0.x + xv.y*w1.x + xv.z*w2.x + xv.w*w3.x;
        acc.y += xv.x*w0.y + xv.y*w1.y + xv.z*w2.y + xv.w*w3.y;
        acc.z += xv.x*w0.z + xv.y*w1.z + xv.z*w2.z + xv.w*w3.z;
        acc.w += xv.x*w0.w + xv.y*w1.w + xv.z*w2.w + xv.w*w3.w;
    }
}

__global__ __launch_bounds__(256) void fused_block_mm(
    const float* __restrict__ x, const float* __restrict__ w,
    const float* __restrict__ bias, float* __restrict__ out)
{
    __shared__ float xs[ROWS_WG * XS_LDW];   // 17,408 B

    const int tid = threadIdx.x;
    const int bx  = blockIdx.x;

    // ---- row-tile-per-XCD remap: XCD x8 walks cj=0..35 of row-tile 8g+x8 ----
    const int x8 = bx & 7;                   // XCD under round-robin dispatch
    const int q  = bx >> 3;                  // 0..1151
    const int cj = q % CHUNKS;               // chunk id 0..35 (wg-uniform)
    const int g  = q / CHUNKS;               // 0..31
    const int rt = (g << 3) + x8;            // row tile 0..255
    const int row_base = rt * ROWS_WG;

    // ---- stage x tile: 64 rows x 64 cols, coalesced float4 ----
    const float* __restrict__ xsrc = x + (size_t)row_base * IN_DIM + cj * 64;
    #pragma unroll
    for (int i = 0; i < 4; ++i) {
        const int f = tid + (i << 8), r = f >> 4, c = (f & 15) << 2;
        *reinterpret_cast<float4*>(&xs[r * XS_LDW + c]) =
            *reinterpret_cast<const float4*>(xsrc + (size_t)r * IN_DIM + c);
    }
    __syncthreads();

    // ---- compute: wave wv -> out cols cj*16+4wv..+3, lane = row ----
    const int wv   = tid >> 6;
    const int lane = tid & 63;
    const int ocol = cj * 16 + (wv << 2);

    float4 acc = *reinterpret_cast<const float4*>(bias + ocol);
    const float* xrow = &xs[lane * XS_LDW];

    if (cj < 4) {
        // group 1: 4 blocks of 16->4; wave's block = wv, k in [16wv, 16wv+16)
        const int woff = __builtin_amdgcn_readfirstlane(cj * 256 + wv * 64);
        col_fma<4, 4>(xrow + (wv << 4), w + woff, acc);
    } else if (cj < 20) {
        // group 2: 2 blocks of 32->8; block = wv>>1, c0 = (wv&1)*4
        const int woff = __builtin_amdgcn_readfirstlane(
            1024 + (cj - 4) * 512 + ((wv >> 1) << 8) + ((wv & 1) << 2));
        col_fma<8, 8>(xrow + ((wv >> 1) << 5), w + woff, acc);
    } else {
        // group 3: 1 dense 64->16 block; c0 = 4wv
        const int woff = __builtin_amdgcn_readfirstlane(
            9216 + (cj - 20) * 1024 + (wv << 2));
        col_fma<16, 16>(xrow, w + woff, acc);
    }

    // ---- store: float4 per lane; 4 waves cover 64 B per row ----
    float* __restrict__ op =
        out + (size_t)(row_base + lane) * OUT_DIM + ocol;
    *reinterpret_cast<float4*>(op) = acc;
}

extern "C" void kernel_launch(void* const* d_in, const int* in_sizes, int n_in,
                              void* d_out, int out_size, void* d_ws, size_t ws_size,
                              hipStream_t stream) {
    const float* x    = (const float*)d_in[0];
    const float* w    = (const float*)d_in[1];
    const float* bias = (const float*)d_in[2];
    float* out        = (float*)d_out;

    const int row_tiles = BATCH / ROWS_WG;           // 256
    fused_block_mm<<<dim3(CHUNKS * row_tiles), 256, 0, stream>>>(
        x, w, bias, out);
}